// Round 13
// baseline (166.674 us; speedup 1.0000x reference)
//
#include <hip/hip_runtime.h>
#include <math.h>

#define MM 64
#define NA 24
#define NP 276
#define NT 6000
#define NTP 6048   // wT/eT rows padded (tail zeroed)
#define NKP 288    // K padded for bf16/MFMA (zero tail)
#define QC 0.22360679774997896f
#define EXPC 0.01666666666666667f  // 5/(3*sig^2), sig=10

// ws layout (float offsets)
#define OFF_XST  0        // xsT[p][m] fp32 276*64 (for k_final)
#define OFF_UU   17664    // 64
#define OFF_VV   17728    // 6000
#define OFF_C1   23728    // 6000
#define OFF_ES   29728    // 64  (zeroed)
#define OFF_SW   29792    // 64  (zeroed)
#define OFF_SH   29856    // 16 shadow arrays [276][64] (zeroed)
#define OFF_WT   312480   // wT[t][m] NTP*64
#define OFF_ET   699552   // eT[t][m] NTP*64
#define OFF_XHL  1086624  // ushort region: xs_hi/lo, xt_hi/lo, Ja_hi/lo (K=288)
#define ZTOT     282752   // ES+SW+SH
// ushort offsets within OFF_XHL region
#define U_XSH 0
#define U_XSL 18432      // 64*288
#define U_XTH 36864
#define U_XTL 1764864    // +6000*288
#define U_JAH 3492864
#define U_JAL 5220864
// total ws = 1086624 + 6948864/2 = 4,561,056 floats = 18.2 MB

typedef __attribute__((ext_vector_type(8))) short bf16x8;
typedef __attribute__((ext_vector_type(4))) float f32x4;

__device__ __forceinline__ unsigned short f2bf(float x) {
  unsigned int u = __float_as_uint(x);
  unsigned int r = (u + 0x7FFFu + ((u >> 16) & 1u)) >> 16;
  return (unsigned short)r;
}
__device__ __forceinline__ float bf2f(unsigned short h) {
  return __uint_as_float(((unsigned int)h) << 16);
}
__device__ __forceinline__ float f4c(const float4& v, int i) {
  return i == 0 ? v.x : i == 1 ? v.y : i == 2 ? v.z : v.w;
}

// ---------- kernel 1: zero + xs build (fp32 + bf16 hi/lo) + xt/Ja bf16 conversion + stats ----------
// blocks 0..63: xs row m; blocks 64..1563: 4 t-rows each (wave per row)
__global__ __launch_bounds__(256) void k_pre(const float* __restrict__ Rs,
                                             const float* __restrict__ xt,
                                             const float* __restrict__ Ja,
                                             float* __restrict__ ws) {
  const int tid = threadIdx.x;
  unsigned short* bfw = (unsigned short*)(ws + OFF_XHL);
  for (int z = blockIdx.x * 256 + tid; z < ZTOT; z += gridDim.x * 256)
    ws[OFF_ES + z] = 0.f;
  for (int z = blockIdx.x * 256 + tid; z < 6144; z += gridDim.x * 256) {
    if (z < 3072) ws[OFF_WT + 384000 + z] = 0.f;
    else          ws[OFF_ET + 384000 + (z - 3072)] = 0.f;
  }

  if (blockIdx.x < MM) {
    const int m = blockIdx.x;
    __shared__ float sR[NA * 3];
    __shared__ float sAcc[4];
    if (tid < NA * 3) sR[tid] = Rs[m * NA * 3 + tid];
    __syncthreads();
    float acc = 0.f;
    for (int p = tid; p < NKP; p += 256) {
      float u = 0.f;
      if (p < NP) {
        int i = (int)((1.0f + sqrtf(1.0f + 8.0f * (float)p)) * 0.5f);
        while (i * (i - 1) / 2 > p) i--;
        while ((i + 1) * i / 2 <= p) i++;
        int j = p - i * (i - 1) / 2;
        float dx = sR[i * 3 + 0] - sR[j * 3 + 0];
        float dy = sR[i * 3 + 1] - sR[j * 3 + 1];
        float dz = sR[i * 3 + 2] - sR[j * 3 + 2];
        u = 1.0f / sqrtf(dx * dx + dy * dy + dz * dz);
        ws[OFF_XST + p * 64 + m] = u;
        acc += u * u;
      }
      const unsigned short hi = f2bf(u);
      const unsigned short lo = f2bf(u - bf2f(hi));
      bfw[U_XSH + m * NKP + p] = hi;
      bfw[U_XSL + m * NKP + p] = lo;
    }
    for (int off = 32; off; off >>= 1) acc += __shfl_down(acc, off);
    if ((tid & 63) == 0) sAcc[tid >> 6] = acc;
    __syncthreads();
    if (tid == 0) ws[OFF_UU + m] = sAcc[0] + sAcc[1] + sAcc[2] + sAcc[3];
  } else {
    const int t = (blockIdx.x - MM) * 4 + (tid >> 6);
    const int lane = tid & 63;
    float a = 0.f, b = 0.f;
#pragma unroll
    for (int it = 0; it < 3; it++) {
      const int k = lane * 2 + it * 128;
      if (k < NKP) {
        float2 v = make_float2(0.f, 0.f), j = v;
        if (k < NP) {
          v = *(const float2*)(xt + (size_t)t * NP + k);
          j = *(const float2*)(Ja + (size_t)t * NP + k);
          a += v.x * v.x + v.y * v.y;
          b += v.x * j.x + v.y * j.y;
        }
        unsigned short vh0 = f2bf(v.x), vh1 = f2bf(v.y);
        unsigned short jh0 = f2bf(j.x), jh1 = f2bf(j.y);
        *(ushort2*)(bfw + U_XTH + (size_t)t * NKP + k) = make_ushort2(vh0, vh1);
        *(ushort2*)(bfw + U_XTL + (size_t)t * NKP + k) =
            make_ushort2(f2bf(v.x - bf2f(vh0)), f2bf(v.y - bf2f(vh1)));
        *(ushort2*)(bfw + U_JAH + (size_t)t * NKP + k) = make_ushort2(jh0, jh1);
        *(ushort2*)(bfw + U_JAL + (size_t)t * NKP + k) =
            make_ushort2(f2bf(j.x - bf2f(jh0)), f2bf(j.y - bf2f(jh1)));
      }
    }
    for (int off = 32; off; off >>= 1) {
      a += __shfl_down(a, off);
      b += __shfl_down(b, off);
    }
    if (lane == 0) { ws[OFF_VV + t] = a; ws[OFF_C1 + t] = b; }
  }
}

// ---------- kernel 2: GEMM1 via split-bf16 MFMA + elementwise ----------
// grid (375 t-tiles, 2 m-halves); block 128 = 2 waves, tile 32m x 16t.
// Wave w: D = 16m x 16t via mfma_f32_16x16x32_bf16, 9 k-steps, 6 MFMA each.
#define SA_HI 0
#define SA_LO 9472       // 32*296
#define SB_XH 18944
#define SB_XL 23680      // +16*296
#define SB_JH 28416
#define SB_JL 33152
#define S_US  37888      // total ushorts = 75,776 B
__global__ __launch_bounds__(128, 2) void k_g1(float* __restrict__ ws) {
  __shared__ __align__(16) unsigned short smem[S_US];
  const int tid = threadIdx.x;
  const int t0 = blockIdx.x * 16;
  const int m0 = blockIdx.y * 32;
  const unsigned short* bfw = (const unsigned short*)(ws + OFF_XHL);

  // stage A: xs hi/lo rows m0..m0+31 (16B chunks; strides 288->296)
  // 2 arrays x (32 rows x 36 chunks) = 2304 chunks  [R12 bug: & with non-pow2 - fixed]
  for (int idx = tid; idx < 2304; idx += 128) {
    const int arr = idx / 1152;           // 0:hi 1:lo
    const int rem = idx - arr * 1152;
    const int row = rem / 36, c = rem - row * 36;
    const unsigned short* src = bfw + (arr ? U_XSL : U_XSH) + (size_t)(m0 + row) * NKP + c * 8;
    *(uint4*)&smem[(arr ? SA_LO : SA_HI) + row * 296 + c * 8] = *(const uint4*)src;
  }
  // stage B: xt/Ja hi/lo rows t0..t0+15: 4 arrays x (16 rows x 36 chunks)
  for (int idx = tid; idx < 2304; idx += 128) {
    const int arr = idx / 576;
    const int rem = idx - arr * 576;
    const int row = rem / 36, c = rem - row * 36;
    const int ubase = (arr == 0) ? U_XTH : (arr == 1) ? U_XTL : (arr == 2) ? U_JAH : U_JAL;
    const int sbase = SB_XH + arr * 4736;
    const unsigned short* src = bfw + ubase + (size_t)(t0 + row) * NKP + c * 8;
    *(uint4*)&smem[sbase + row * 296 + c * 8] = *(const uint4*)src;
  }
  __syncthreads();

  const int ln = tid & 63, w = tid >> 6;
  const int tcol = ln & 15;      // t-local (D col, B row)
  const int qr = ln >> 4;        // k-segment for operands; m-quad for D
  const int aoff = (w * 16 + tcol) * 296 + qr * 8;
  const int boff = tcol * 296 + qr * 8;

  f32x4 accv = {0.f, 0.f, 0.f, 0.f};
  f32x4 accj = {0.f, 0.f, 0.f, 0.f};
#pragma unroll
  for (int ks = 0; ks < 9; ks++) {
    const int k0 = ks * 32;
    const bf16x8 ah  = *(const bf16x8*)&smem[SA_HI + aoff + k0];
    const bf16x8 al  = *(const bf16x8*)&smem[SA_LO + aoff + k0];
    const bf16x8 bxh = *(const bf16x8*)&smem[SB_XH + boff + k0];
    const bf16x8 bxl = *(const bf16x8*)&smem[SB_XL + boff + k0];
    const bf16x8 bjh = *(const bf16x8*)&smem[SB_JH + boff + k0];
    const bf16x8 bjl = *(const bf16x8*)&smem[SB_JL + boff + k0];
    accv = __builtin_amdgcn_mfma_f32_16x16x32_bf16(ah, bxh, accv, 0, 0, 0);
    accv = __builtin_amdgcn_mfma_f32_16x16x32_bf16(ah, bxl, accv, 0, 0, 0);
    accv = __builtin_amdgcn_mfma_f32_16x16x32_bf16(al, bxh, accv, 0, 0, 0);
    accj = __builtin_amdgcn_mfma_f32_16x16x32_bf16(ah, bjh, accj, 0, 0, 0);
    accj = __builtin_amdgcn_mfma_f32_16x16x32_bf16(ah, bjl, accj, 0, 0, 0);
    accj = __builtin_amdgcn_mfma_f32_16x16x32_bf16(al, bjh, accj, 0, 0, 0);
  }

  // epilogue: D[row][col] with row = m-local = w*16 + qr*4 + i, col = t-local = tcol
  const int m = m0 + w * 16 + qr * 4;
  const int t = t0 + tcol;
  const float4 uu4 = *(const float4*)(ws + OFF_UU + m);
  const float vvt = ws[OFF_VV + t];
  const float c1t = ws[OFF_C1 + t];
  float wq[4], eq[4], es4[4], sw4[4];
#pragma unroll
  for (int i = 0; i < 4; i++) {
    const float g1v = accv[i];
    const float g2v = accj[i];
    float d2 = fmaxf(f4c(uu4, i) - 2.f * g1v + vvt, 0.f);
    float xd = QC * sqrtf(d2);
    float dv = QC * (g2v - c1t);
    float ex = EXPC * __expf(-xd);
    float e1v = ex * (1.f + xd);
    float w_ = ex * dv;
    wq[i] = w_; eq[i] = e1v;
    es4[i] = e1v * dv;
    sw4[i] = w_;
  }
  *(float4*)(ws + OFF_WT + (size_t)t * 64 + m) = make_float4(wq[0], wq[1], wq[2], wq[3]);
  *(float4*)(ws + OFF_ET + (size_t)t * 64 + m) = make_float4(eq[0], eq[1], eq[2], eq[3]);
#pragma unroll
  for (int off = 8; off; off >>= 1) {
#pragma unroll
    for (int i = 0; i < 4; i++) {
      es4[i] += __shfl_down(es4[i], off, 16);
      sw4[i] += __shfl_down(sw4[i], off, 16);
    }
  }
  if (tcol == 0) {
#pragma unroll
    for (int i = 0; i < 4; i++) {
      atomicAdd(ws + OFF_ES + m + i, es4[i]);
      atomicAdd(ws + OFF_SW + m + i, sw4[i]);
    }
  }
}

// ---------- kernel 3: GEMM2 partials (R8-verbatim), shadow atomics ----------
#define G2_KC 96
__global__ __launch_bounds__(256, 2) void k_g2(const float* __restrict__ xt,
                                               const float* __restrict__ Ja,
                                               float* __restrict__ ws) {
  __shared__ __align__(16) float Aw[G2_KC][68];
  __shared__ __align__(16) float Ae[G2_KC][68];
  __shared__ __align__(16) float2 Bvj[G2_KC][18];
  const int tid = threadIdx.x;
  const int p0 = blockIdx.x * 16;
  const int k0 = blockIdx.y * G2_KC;
  const int validp = (NP - p0 < 16) ? (NP - p0) : 16;

  for (int idx = tid; idx < G2_KC * 16; idx += 256) {
    const int k = idx >> 4;
    const int mq = (idx & 15) * 4;
    *(float4*)&Aw[k][mq] = *(const float4*)(ws + OFF_WT + (size_t)(k0 + k) * 64 + mq);
    *(float4*)&Ae[k][mq] = *(const float4*)(ws + OFF_ET + (size_t)(k0 + k) * 64 + mq);
  }
  for (int idx = tid; idx < G2_KC * 4; idx += 256) {
    const int k = idx >> 2;
    const int pq = (idx & 3) * 4;
    const int t = k0 + k;
    float4 v = make_float4(0.f, 0.f, 0.f, 0.f), j = v;
    if (pq < validp && t < NT) {
      v = *(const float4*)(xt + (size_t)t * NP + p0 + pq);
      j = *(const float4*)(Ja + (size_t)t * NP + p0 + pq);
    }
    *(float4*)&Bvj[k][pq]     = make_float4(v.x, j.x, v.y, j.y);
    *(float4*)&Bvj[k][pq + 2] = make_float4(v.z, j.z, v.w, j.w);
  }
  __syncthreads();

  const int r = tid & 31;
  const int c = tid >> 5;
  float f1[2][2] = {{0.f, 0.f}, {0.f, 0.f}};
  float f2[2][2] = {{0.f, 0.f}, {0.f, 0.f}};
#pragma unroll 4
  for (int k = 0; k < G2_KC; k++) {
    const float2 aw = *(const float2*)&Aw[k][2 * r];
    const float2 ae = *(const float2*)&Ae[k][2 * r];
    const float4 b  = *(const float4*)&Bvj[k][2 * c];
    f1[0][0] = fmaf(aw.x, b.x, f1[0][0]); f1[0][1] = fmaf(aw.x, b.z, f1[0][1]);
    f1[1][0] = fmaf(aw.y, b.x, f1[1][0]); f1[1][1] = fmaf(aw.y, b.z, f1[1][1]);
    f2[0][0] = fmaf(ae.x, b.y, f2[0][0]); f2[0][1] = fmaf(ae.x, b.w, f2[0][1]);
    f2[1][0] = fmaf(ae.y, b.y, f2[1][0]); f2[1][1] = fmaf(ae.y, b.w, f2[1][1]);
  }

  const int sh = blockIdx.y & 7;
  float* b1 = ws + OFF_SH + (size_t)(sh * 2 + 0) * NP * 64;
  float* b2 = ws + OFF_SH + (size_t)(sh * 2 + 1) * NP * 64;
#pragma unroll
  for (int j = 0; j < 2; j++) {
    const int pl = 2 * c + j;
    if (pl < validp) {
      const int p = p0 + pl;
#pragma unroll
      for (int i = 0; i < 2; i++) {
        atomicAdd(b1 + (size_t)p * 64 + 2 * r + i, f1[i][j]);
        atomicAdd(b2 + (size_t)p * 64 + 2 * r + i, f2[i][j]);
      }
    }
  }
}

// ---------- kernel 4: finalize ----------
__global__ __launch_bounds__(320) void k_final(const float* __restrict__ Rs,
                                               const float* __restrict__ ws,
                                               float* __restrict__ out) {
  const int m = blockIdx.x;
  const int tid = threadIdx.x;
  __shared__ float fx[NP];
  __shared__ float sR[NA * 3];
  if (tid < NA * 3) sR[tid] = Rs[m * NA * 3 + tid];
  const float sw = ws[OFF_SW + m];
  for (int p = tid; p < NP; p += 320) {
    float f1p = 0.f, f2 = 0.f;
#pragma unroll
    for (int s = 0; s < 8; s++) {
      f1p += ws[OFF_SH + ((size_t)(s * 2 + 0) * NP + p) * 64 + m];
      f2  += ws[OFF_SH + ((size_t)(s * 2 + 1) * NP + p) * 64 + m];
    }
    const float u = ws[OFF_XST + p * 64 + m];
    const float F1 = QC * (u * sw - f1p);
    fx[p] = (F1 - f2) * u * u * u;
  }
  __syncthreads();
  if (tid == 0) out[m] = ws[OFF_ES + m] / QC;  // *STD + C, STD=1, C=0
  if (tid < NA * 3) {
    const int a = tid / 3, cc = tid % 3;
    const float ra = sR[a * 3 + cc];
    float acc = 0.f;
    for (int b = 0; b < NA; b++) {
      if (b == a) continue;
      const int i = a > b ? a : b, j = a > b ? b : a;
      const int p = i * (i - 1) / 2 + j;
      acc += (sR[b * 3 + cc] - ra) * fx[p];
    }
    out[MM + m * NA * 3 + tid] = acc;
  }
}

extern "C" void kernel_launch(void* const* d_in, const int* in_sizes, int n_in,
                              void* d_out, int out_size, void* d_ws, size_t ws_size,
                              hipStream_t stream) {
  const float* Rs = (const float*)d_in[0];
  const float* xt = (const float*)d_in[1];
  const float* Ja = (const float*)d_in[2];
  float* out = (float*)d_out;
  float* ws = (float*)d_ws;

  k_pre<<<MM + NT / 4, 256, 0, stream>>>(Rs, xt, Ja, ws);
  k_g1<<<dim3(375, 2), 128, 0, stream>>>(ws);
  k_g2<<<dim3(18, 63), 256, 0, stream>>>(xt, Ja, ws);
  k_final<<<MM, 320, 0, stream>>>(Rs, ws, out);
}